// Round 1
// 321.777 us; speedup vs baseline: 1.1720x; 1.1720x over previous
//
#include <hip/hip_runtime.h>
#include <hip/hip_bf16.h>
#include <hip/hip_fp16.h>
#include <math.h>

#define N_NODES 50000
#define N_EDGES 600000
#define E_TOT   (N_EDGES + N_NODES)   // 650000 edges incl self-loops
#define F       128
#define HEADS   4
#define DHEAD   32
#define CLS     10
#define CLS_PAD 16

// ---------------- CSR build ----------------

__global__ void count_deg(const int* __restrict__ ei, int* __restrict__ deg) {
    int e = blockIdx.x * blockDim.x + threadIdx.x;
    if (e >= E_TOT) return;
    int d = (e < N_EDGES) ? ei[N_EDGES + e] : (e - N_EDGES);
    atomicAdd(&deg[d], 1);
}

#define SCAN_BLOCK 256
#define SCAN_ITEMS 4   // chunk = 1024

__global__ void scan1(const int* __restrict__ deg, int* __restrict__ ptr,
                      int* __restrict__ blockSums, int n) {
    __shared__ int sdata[SCAN_BLOCK];
    int t = threadIdx.x;
    int base = blockIdx.x * (SCAN_BLOCK * SCAN_ITEMS) + t * SCAN_ITEMS;
    int v[SCAN_ITEMS];
    int sum = 0;
    #pragma unroll
    for (int i = 0; i < SCAN_ITEMS; i++) {
        int idx = base + i;
        v[i] = (idx < n) ? deg[idx] : 0;
        sum += v[i];
    }
    sdata[t] = sum;
    __syncthreads();
    for (int off = 1; off < SCAN_BLOCK; off <<= 1) {
        int x = 0;
        if (t >= off) x = sdata[t - off];
        __syncthreads();
        if (t >= off) sdata[t] += x;
        __syncthreads();
    }
    int excl = (t > 0) ? sdata[t - 1] : 0;
    if (t == SCAN_BLOCK - 1) blockSums[blockIdx.x] = sdata[t];
    int run = excl;
    #pragma unroll
    for (int i = 0; i < SCAN_ITEMS; i++) {
        int idx = base + i;
        if (idx < n) ptr[idx] = run;
        run += v[i];
    }
}

__global__ void scan2(int* __restrict__ blockSums, int nb) {
    if (threadIdx.x == 0 && blockIdx.x == 0) {
        int run = 0;
        for (int i = 0; i < nb; i++) { int v = blockSums[i]; blockSums[i] = run; run += v; }
    }
}

__global__ void scan3(int* __restrict__ ptr, const int* __restrict__ blockSums,
                      int* __restrict__ cursor, int n, int total) {
    int i = blockIdx.x * blockDim.x + threadIdx.x;
    if (i < n) {
        int v = ptr[i] + blockSums[i / (SCAN_BLOCK * SCAN_ITEMS)];
        ptr[i] = v;
        cursor[i] = v;
    }
    if (i == 0) ptr[n] = total;
}

__global__ void scatter_edges(const int* __restrict__ ei, int* __restrict__ cursor,
                              int* __restrict__ csr_src) {
    int e = blockIdx.x * blockDim.x + threadIdx.x;
    if (e >= E_TOT) return;
    int s, d;
    if (e < N_EDGES) { s = ei[e]; d = ei[N_EDGES + e]; }
    else             { s = d = e - N_EDGES; }
    int pos = atomicAdd(&cursor[d], 1);
    csr_src[pos] = s;
}

// ---------------- W pre-convert: fp32 [k][c] -> fp16 transposed [c][k], XOR-swizzled ----------------
// swizzle: element k of row c stored at k ^ ((c&7)<<3)  (moves 8-elem/16B groups within the row)

__global__ __launch_bounds__(256) void conv_w(const float* __restrict__ W0,
                                              const float* __restrict__ W1,
                                              __half* __restrict__ Wt0,
                                              __half* __restrict__ Wt1) {
    int idx = blockIdx.x * 256 + threadIdx.x;
    if (idx >= 128 * 128) return;
    int k = idx >> 7, c = idx & 127;
    int e = k ^ ((c & 7) << 3);
    Wt0[c * 128 + e] = __float2half(W0[idx]);
    Wt1[c * 128 + e] = __float2half(W1[idx]);
}

// ---------------- MFMA GEMM + fused attention coefficients ----------------
// 64-row tile x 128 cols, 256 threads = 4 waves, each wave: 16 rows x 128 cols.
// A: fp32 global -> fp16 swizzled LDS (reg-staged convert). B: pre-swizzled fp16 Wt (linear copy).
// Fragment reads are ds_read_b128, XOR-swizzle -> 2-way (free) bank aliasing.
// C/D layout (m89-verified): col = lane&15, row = (lane>>4)*4 + reg.

using half8_t  = __attribute__((ext_vector_type(8))) _Float16;
using floatx4  = __attribute__((ext_vector_type(4))) float;

__global__ __launch_bounds__(256) void gemm_att_mfma(const float* __restrict__ A,
                                                     const __half* __restrict__ Wt,
                                                     const float* __restrict__ att_s,
                                                     const float* __restrict__ att_d,
                                                     __half* __restrict__ C,
                                                     float* __restrict__ a_s,
                                                     float* __restrict__ a_d, int nrows) {
    __shared__ _Float16 As[64 * 128];    // 16 KB, swizzled rows
    __shared__ _Float16 Ws[128 * 128];   // 32 KB, pre-swizzled [col][k]
    int t = threadIdx.x;
    int row0 = blockIdx.x * 64;

    // stage Ws: linear 32 KB copy (Wt already transposed+swizzled)
    #pragma unroll
    for (int idx = t; idx < 128 * 128 / 8; idx += 256)
        ((float4*)Ws)[idx] = ((const float4*)Wt)[idx];

    // stage As: 64 rows x 16 groups of 8 elems; convert fp32->fp16, swizzled write
    #pragma unroll
    for (int idx = t; idx < 64 * 16; idx += 256) {
        int r = idx >> 4, g = idx & 15;
        float4 v0 = make_float4(0.f, 0.f, 0.f, 0.f), v1 = v0;
        if (row0 + r < nrows) {
            const float4* p = (const float4*)(A + (size_t)(row0 + r) * 128 + g * 8);
            v0 = p[0]; v1 = p[1];
        }
        int gs = g ^ (r & 7);
        union { _Float16 h[8]; float4 f; } u;
        u.h[0] = (_Float16)v0.x; u.h[1] = (_Float16)v0.y;
        u.h[2] = (_Float16)v0.z; u.h[3] = (_Float16)v0.w;
        u.h[4] = (_Float16)v1.x; u.h[5] = (_Float16)v1.y;
        u.h[6] = (_Float16)v1.z; u.h[7] = (_Float16)v1.w;
        *(float4*)&As[r * 128 + (gs << 3)] = u.f;
    }
    __syncthreads();

    int wave = t >> 6, l = t & 63;
    int lr = l & 15, lg = l >> 4;        // lr: col/row-in-frag lane, lg: k-group
    int arow = wave * 16 + lr;           // A row within tile (A-frag row = lane&15)

    floatx4 acc[8];
    #pragma unroll
    for (int c2 = 0; c2 < 8; c2++) acc[c2] = (floatx4){0.f, 0.f, 0.f, 0.f};

    #pragma unroll
    for (int ks = 0; ks < 4; ks++) {
        int gk = ks * 4 + lg;            // k-group index (k = gk*8 .. +7)
        half8_t af = *(const half8_t*)&As[arow * 128 + ((gk ^ (arow & 7)) << 3)];
        #pragma unroll
        for (int c2 = 0; c2 < 8; c2++) {
            int col = c2 * 16 + lr;
            half8_t bf = *(const half8_t*)&Ws[col * 128 + ((gk ^ (col & 7)) << 3)];
            acc[c2] = __builtin_amdgcn_mfma_f32_16x16x32_f16(af, bf, acc[c2], 0, 0, 0);
        }
    }

    // store C tile (fp16). C/D: col = lane&15 (per frag), row = lg*4 + reg.
    #pragma unroll
    for (int c2 = 0; c2 < 8; c2++) {
        int col = c2 * 16 + lr;
        #pragma unroll
        for (int r = 0; r < 4; r++) {
            int row = row0 + wave * 16 + lg * 4 + r;
            if (row < nrows) C[(size_t)row * 128 + col] = __float2half(acc[c2][r]);
        }
    }

    // fused attention coefficients from fp32 accumulators.
    // head h covers col-frags 2h, 2h+1. Reduce over the 16 col-lanes via shfl_xor.
    float asv[8], adv8[8];
    #pragma unroll
    for (int c2 = 0; c2 < 8; c2++) {
        asv[c2]  = att_s[c2 * 16 + lr];
        adv8[c2] = att_d[c2 * 16 + lr];
    }
    float ps[4][4], pd[4][4];
    #pragma unroll
    for (int r = 0; r < 4; r++)
        #pragma unroll
        for (int hh = 0; hh < 4; hh++) {
            ps[r][hh] = acc[2 * hh][r] * asv[2 * hh] + acc[2 * hh + 1][r] * asv[2 * hh + 1];
            pd[r][hh] = acc[2 * hh][r] * adv8[2 * hh] + acc[2 * hh + 1][r] * adv8[2 * hh + 1];
        }
    #pragma unroll
    for (int m = 1; m <= 8; m <<= 1) {
        #pragma unroll
        for (int r = 0; r < 4; r++)
            #pragma unroll
            for (int hh = 0; hh < 4; hh++) {
                ps[r][hh] += __shfl_xor(ps[r][hh], m);
                pd[r][hh] += __shfl_xor(pd[r][hh], m);
            }
    }
    if (lr == 0) {
        #pragma unroll
        for (int r = 0; r < 4; r++) {
            int row = row0 + wave * 16 + lg * 4 + r;
            if (row < nrows) {
                *(float4*)(a_s + (size_t)row * 4) = make_float4(ps[r][0], ps[r][1], ps[r][2], ps[r][3]);
                *(float4*)(a_d + (size_t)row * 4) = make_float4(pd[r][0], pd[r][1], pd[r][2], pd[r][3]);
            }
        }
    }
}

// ---------------- single-pass aggregate, exp fused in (no ex buffer) ----------------
// 2 nodes/block, 64 threads/node, half2 per lane (2 cols). Per edge each thread
// computes its head's exp(leaky_relu(a_s[src]+a_d[dst])) inline.

__global__ __launch_bounds__(128) void gat_aggr(const __half2* __restrict__ hp,
                                                const float* __restrict__ a_s,
                                                const float* __restrict__ a_d,
                                                const int* __restrict__ ptr,
                                                const int* __restrict__ csr,
                                                const float* __restrict__ bias,
                                                const float* __restrict__ gamma,
                                                const float* __restrict__ beta,
                                                float* __restrict__ out) {
    int t = threadIdx.x;
    int node = blockIdx.x * 2 + (t >> 6);
    int local = t & 63;
    int h = local >> 4;
    int beg = ptr[node], end = ptr[node + 1];
    float adh = a_d[(size_t)node * 4 + h];
    float ax = 0.f, ay = 0.f, l = 0.f;
    int i = beg;
    for (; i + 3 < end; i += 4) {
        int s0 = csr[i], s1 = csr[i + 1], s2 = csr[i + 2], s3 = csr[i + 3];
        float al0 = a_s[(size_t)s0 * 4 + h] + adh;
        float al1 = a_s[(size_t)s1 * 4 + h] + adh;
        float al2 = a_s[(size_t)s2 * 4 + h] + adh;
        float al3 = a_s[(size_t)s3 * 4 + h] + adh;
        al0 = (al0 > 0.f) ? al0 : 0.2f * al0;
        al1 = (al1 > 0.f) ? al1 : 0.2f * al1;
        al2 = (al2 > 0.f) ? al2 : 0.2f * al2;
        al3 = (al3 > 0.f) ? al3 : 0.2f * al3;
        float w0 = __expf(al0), w1 = __expf(al1), w2 = __expf(al2), w3 = __expf(al3);
        float2 v0 = __half22float2(hp[(size_t)s0 * 64 + local]);
        float2 v1 = __half22float2(hp[(size_t)s1 * 64 + local]);
        float2 v2 = __half22float2(hp[(size_t)s2 * 64 + local]);
        float2 v3 = __half22float2(hp[(size_t)s3 * 64 + local]);
        l  += w0 + w1 + w2 + w3;
        ax += w0 * v0.x + w1 * v1.x + w2 * v2.x + w3 * v3.x;
        ay += w0 * v0.y + w1 * v1.y + w2 * v2.y + w3 * v3.y;
    }
    for (; i < end; i++) {
        int s0 = csr[i];
        float al = a_s[(size_t)s0 * 4 + h] + adh;
        al = (al > 0.f) ? al : 0.2f * al;
        float w = __expf(al);
        float2 v = __half22float2(hp[(size_t)s0 * 64 + local]);
        l  += w;
        ax += w * v.x;
        ay += w * v.y;
    }
    float inv = 1.f / (l + 1e-16f);
    int c = local * 2;
    const float rs = rsqrtf(1.f + 1e-5f);
    float vx = ax * inv + bias[c];
    float vy = ay * inv + bias[c + 1];
    vx = vx * (gamma[c] * rs) + beta[c];
    vy = vy * (gamma[c + 1] * rs) + beta[c + 1];
    vx = (vx > 0.f) ? vx : expm1f(vx);
    vy = (vy > 0.f) ? vy : expm1f(vy);
    *(float2*)(out + (size_t)node * 128 + c) = make_float2(vx, vy);
}

// ---------------- layer 2: fused [N,128]@[128,10] GEMM + coefficients ----------------

__global__ __launch_bounds__(256) void cls_fused(const float* __restrict__ A,
                                                 const float* __restrict__ W2,
                                                 const float* __restrict__ as2,
                                                 const float* __restrict__ ad2,
                                                 float* __restrict__ hp2,
                                                 float* __restrict__ asn,
                                                 float* __restrict__ adn) {
    __shared__ float W2s[128 * CLS];
    __shared__ float av[2 * CLS];
    int t = threadIdx.x;
    for (int idx = t; idx < 128 * CLS; idx += 256) W2s[idx] = W2[idx];
    if (t < CLS) av[t] = as2[t];
    else if (t < 2 * CLS) av[t] = ad2[t - CLS];
    __syncthreads();

    int node = blockIdx.x * 64 + (t >> 2);
    int q = t & 3;
    if (node >= N_NODES) return;
    float acc[CLS];
    #pragma unroll
    for (int c = 0; c < CLS; c++) acc[c] = 0.f;
    const float4* arow = (const float4*)(A + (size_t)node * 128) + q * 8;
    #pragma unroll
    for (int kk = 0; kk < 8; kk++) {
        float4 a = arow[kk];
        int k = q * 32 + kk * 4;
        #pragma unroll
        for (int c = 0; c < CLS; c++) {
            acc[c] += a.x * W2s[(k + 0) * CLS + c] + a.y * W2s[(k + 1) * CLS + c]
                    + a.z * W2s[(k + 2) * CLS + c] + a.w * W2s[(k + 3) * CLS + c];
        }
    }
    #pragma unroll
    for (int c = 0; c < CLS; c++) {
        acc[c] += __shfl_xor(acc[c], 1, 4);
        acc[c] += __shfl_xor(acc[c], 2, 4);
    }
    if (q == 0) {
        float s = 0.f, d = 0.f;
        float* row = hp2 + (size_t)node * CLS_PAD;
        #pragma unroll
        for (int c = 0; c < CLS; c++) {
            row[c] = acc[c];
            s += acc[c] * av[c];
            d += acc[c] * av[CLS + c];
        }
        asn[node] = s;
        adn[node] = d;
    }
}

__global__ __launch_bounds__(256) void gat_aggr2(const float* __restrict__ hp2,
                                                 const float* __restrict__ asn,
                                                 const float* __restrict__ adn,
                                                 const int* __restrict__ ptr,
                                                 const int* __restrict__ csr,
                                                 const float* __restrict__ b2,
                                                 float* __restrict__ out) {
    int gid = blockIdx.x * blockDim.x + threadIdx.x;
    int node = gid >> 4;
    int c = gid & 15;
    if (node >= N_NODES) return;
    int beg = ptr[node], end = ptr[node + 1];
    int cc = (c < CLS) ? c : 0;
    float adv = adn[node];
    float acc = 0.f, l = 0.f;
    int i = beg;
    for (; i + 1 < end; i += 2) {
        int s0 = csr[i], s1 = csr[i + 1];
        float al0 = asn[s0] + adv;
        float al1 = asn[s1] + adv;
        al0 = (al0 > 0.f) ? al0 : 0.2f * al0;
        al1 = (al1 > 0.f) ? al1 : 0.2f * al1;
        float w0 = __expf(al0), w1 = __expf(al1);
        float v0 = hp2[(size_t)s0 * CLS_PAD + cc];
        float v1 = hp2[(size_t)s1 * CLS_PAD + cc];
        l += w0 + w1;
        acc += w0 * v0 + w1 * v1;
    }
    if (i < end) {
        int s0 = csr[i];
        float al = asn[s0] + adv;
        al = (al > 0.f) ? al : 0.2f * al;
        float w = __expf(al);
        l += w;
        acc += w * hp2[(size_t)s0 * CLS_PAD + cc];
    }
    if (c < CLS) out[(size_t)node * CLS + c] = acc / (l + 1e-16f) + b2[c];
}

// ---------------- launch ----------------

extern "C" void kernel_launch(void* const* d_in, const int* in_sizes, int n_in,
                              void* d_out, int out_size, void* d_ws, size_t ws_size,
                              hipStream_t stream) {
    const float* x   = (const float*)d_in[0];
    const int*   ei  = (const int*)  d_in[1];
    const float* W0  = (const float*)d_in[2];
    const float* as0 = (const float*)d_in[3];
    const float* ad0 = (const float*)d_in[4];
    const float* b0  = (const float*)d_in[5];
    const float* g0  = (const float*)d_in[6];
    const float* be0 = (const float*)d_in[7];
    const float* W1  = (const float*)d_in[8];
    const float* as1 = (const float*)d_in[9];
    const float* ad1 = (const float*)d_in[10];
    const float* b1  = (const float*)d_in[11];
    const float* g1  = (const float*)d_in[12];
    const float* be1 = (const float*)d_in[13];
    const float* W2  = (const float*)d_in[14];
    const float* as2 = (const float*)d_in[15];
    const float* ad2 = (const float*)d_in[16];
    const float* b2  = (const float*)d_in[17];

    char* ws = (char*)d_ws;
    size_t off = 0;
    auto alloc = [&](size_t bytes) -> void* {
        void* p = ws + off;
        off += (bytes + 255) & ~(size_t)255;
        return p;
    };
    int*    ptr    = (int*)   alloc((N_NODES + 1) * sizeof(int));
    int*    cursor = (int*)   alloc(N_NODES * sizeof(int));
    int*    bsums  = (int*)   alloc(64 * sizeof(int));
    int*    csr    = (int*)   alloc(E_TOT * sizeof(int));
    __half* hp     = (__half*)alloc((size_t)N_NODES * 128 * sizeof(__half));
    float*  hc     = (float*) alloc((size_t)N_NODES * 128 * sizeof(float));
    float*  a_s    = (float*) alloc(N_NODES * 4 * sizeof(float));
    float*  a_d    = (float*) alloc(N_NODES * 4 * sizeof(float));
    float*  hp2    = (float*) alloc((size_t)N_NODES * CLS_PAD * sizeof(float));
    float*  asn    = (float*) alloc(N_NODES * sizeof(float));
    float*  adn    = (float*) alloc(N_NODES * sizeof(float));
    __half* Wt0    = (__half*)alloc(128 * 128 * sizeof(__half));
    __half* Wt1    = (__half*)alloc(128 * 128 * sizeof(__half));

    // ---- CSR build ----
    hipMemsetAsync(cursor, 0, N_NODES * sizeof(int), stream);
    count_deg<<<(E_TOT + 255) / 256, 256, 0, stream>>>(ei, cursor);
    int nScanBlocks = (N_NODES + SCAN_BLOCK * SCAN_ITEMS - 1) / (SCAN_BLOCK * SCAN_ITEMS);
    scan1<<<nScanBlocks, SCAN_BLOCK, 0, stream>>>(cursor, ptr, bsums, N_NODES);
    scan2<<<1, 64, 0, stream>>>(bsums, nScanBlocks);
    scan3<<<(N_NODES + 255) / 256, 256, 0, stream>>>(ptr, bsums, cursor, N_NODES, E_TOT);
    scatter_edges<<<(E_TOT + 255) / 256, 256, 0, stream>>>(ei, cursor, csr);

    // ---- weight pre-convert (independent of CSR) ----
    conv_w<<<64, 256, 0, stream>>>(W0, W1, Wt0, Wt1);

    int gemmBlocks = (N_NODES + 63) / 64;

    // ---- layer 0 ----
    gemm_att_mfma<<<gemmBlocks, 256, 0, stream>>>(x, Wt0, as0, ad0, hp, a_s, a_d, N_NODES);
    gat_aggr<<<N_NODES / 2, 128, 0, stream>>>((const __half2*)hp, a_s, a_d, ptr, csr,
                                              b0, g0, be0, hc);

    // ---- layer 1 ----
    gemm_att_mfma<<<gemmBlocks, 256, 0, stream>>>(hc, Wt1, as1, ad1, hp, a_s, a_d, N_NODES);
    gat_aggr<<<N_NODES / 2, 128, 0, stream>>>((const __half2*)hp, a_s, a_d, ptr, csr,
                                              b1, g1, be1, hc);

    // ---- layer 2 ----
    cls_fused<<<(N_NODES + 63) / 64, 256, 0, stream>>>(hc, W2, as2, ad2, hp2, asn, adn);
    gat_aggr2<<<(N_NODES * 16 + 255) / 256, 256, 0, stream>>>(hp2, asn, adn, ptr, csr, b2,
                                                              (float*)d_out);
}